// Round 9
// baseline (460.510 us; speedup 1.0000x reference)
//
#include <hip/hip_runtime.h>
#include <hip/hip_cooperative_groups.h>
#include <hip/hip_bf16.h>
#include <stdint.h>

#define N_NODES 4096
#define INF_ 512
#define OUTF_ 512

namespace cg = cooperative_groups;

typedef unsigned short u16;
typedef __attribute__((ext_vector_type(8))) short bf16x8;
typedef __attribute__((ext_vector_type(4))) float f32x4;

__device__ __forceinline__ u16 f2bf(float f) {
    union { float f; uint32_t u; } v; v.f = f;
    uint32_t u = v.u;
    uint32_t r = u + 0x7FFFu + ((u >> 16) & 1u);   // round-to-nearest-even
    return (u16)(r >> 16);
}

__device__ __forceinline__ void async16(const void* gsrc, void* ldst) {
    __builtin_amdgcn_global_load_lds(
        (const __attribute__((address_space(1))) unsigned int*)gsrc,
        (__attribute__((address_space(3))) unsigned int*)ldst,
        16, 0, 0);
}

// ---- convert X -> bf16 row-major, W -> bf16 transposed [OUTF][INF] ----
__global__ void convert_kernel(const float* __restrict__ X, const float* __restrict__ W,
                               u16* __restrict__ Xbf, u16* __restrict__ WT) {
    int tid = blockIdx.x * blockDim.x + threadIdx.x;
    if (tid < N_NODES * INF_) Xbf[tid] = f2bf(X[tid]);
    if (tid < INF_ * OUTF_) {
        int n = tid >> 9, k = tid & 511;
        WT[tid] = f2bf(W[k * OUTF_ + n]);   // WT[n][k] = W[k][n]
    }
}

// ---- gemm1: ST = (X @ W)^T bf16. 64x128 tile, BK=32, 4 waves. (verified R2-R8) ----
__global__ __launch_bounds__(256)
void gemm_support(const u16* __restrict__ A, const u16* __restrict__ B,
                  u16* __restrict__ outT) {
    const int K = 512;
    __shared__ u16 As[64][32];
    __shared__ u16 Bs[128][32];

    const int tid  = threadIdx.x;
    const int lane = tid & 63;
    const int w    = tid >> 6;
    const int wr   = w >> 1;
    const int wc   = w & 1;
    const int brow = blockIdx.x * 64;
    const int bcol = blockIdx.y * 128;

    f32x4 acc[2][4] = {};

    const int srA = w * 16 + (lane >> 2);
    const int srB = w * 32 + (lane >> 2);
    const int sc  = (lane & 3) * 8;

    for (int kt = 0; kt < K; kt += 32) {
        __syncthreads();
        async16(&A[(long)(brow + srA) * K + kt + sc],      &As[w * 16][0]);
        async16(&B[(long)(bcol + srB) * K + kt + sc],      &Bs[w * 32][0]);
        async16(&B[(long)(bcol + srB + 16) * K + kt + sc], &Bs[w * 32 + 16][0]);
        __syncthreads();

        bf16x8 af[2], bfr[4];
#pragma unroll
        for (int m = 0; m < 2; ++m)
            af[m] = *(const bf16x8*)&As[wr * 32 + m * 16 + (lane & 15)][(lane >> 4) * 8];
#pragma unroll
        for (int n = 0; n < 4; ++n)
            bfr[n] = *(const bf16x8*)&Bs[wc * 64 + n * 16 + (lane & 15)][(lane >> 4) * 8];
#pragma unroll
        for (int m = 0; m < 2; ++m)
#pragma unroll
            for (int n = 0; n < 4; ++n)
                acc[m][n] = __builtin_amdgcn_mfma_f32_16x16x32_bf16(af[m], bfr[n], acc[m][n], 0, 0, 0);
    }

#pragma unroll
    for (int m = 0; m < 2; ++m)
#pragma unroll
        for (int n = 0; n < 4; ++n) {
            int col  = bcol + wc * 64 + n * 16 + (lane & 15);
            int row0 = brow + wr * 32 + m * 16 + (lane >> 4) * 4;
#pragma unroll
            for (int r = 0; r < 4; ++r)
                outT[(long)col * N_NODES + row0 + r] = f2bf(acc[m][n][r]);
        }
}

// ---- cooperative fused: out = reshape(E@wq) @ S + bias ----
// 256 blocks x 512 thr (8 waves), 1 block/CU. K=4096 in 4 chunks of 1024.
// Per chunk: blocks cooperatively prep E->bf16 into Abuf[(z+1)&1] (each thread
// 32 float4, in 4 groups of 8 interleaved with the MFMA iters) while computing
// chunk z from Abuf[z&1] with the R2-proven 2-barrier BK=32 loop (tile 64x128,
// wave-tile 32x32). grid.sync() per chunk hands off. acc persists -> no parts.
__global__ __launch_bounds__(512, 2)
void coop_fused(const float4* __restrict__ E4, const float* __restrict__ wq,
                const u16* __restrict__ ST, const float* __restrict__ bias,
                u16* __restrict__ Abuf0, u16* __restrict__ Abuf1,
                float* __restrict__ out) {
    cg::grid_group grid = cg::this_grid();
    __shared__ u16 As[64][32];
    __shared__ u16 Bs[128][32];

    const int tid  = threadIdx.x;
    const int lane = tid & 63;
    const int w    = tid >> 6;                 // 0..7
    const int bid  = blockIdx.x;               // 0..255
    const int brow = (bid >> 2) * 64;
    const int bcol = (bid & 3) * 128;
    const int gt   = bid * 512 + tid;          // 0..131071

    const float w0 = wq[0], w1 = wq[1], w2 = wq[2], w3 = wq[3];

    // staging roles (R2 pattern): A = 4 instrs (waves 0-3), B = 8 instrs (one/wave)
    const int srA = (w & 3) * 16 + (lane >> 2);
    const int srB = w * 16 + (lane >> 2);
    const int sc  = (lane & 3) * 8;

    // fragment roles: wave-grid 2x4, wave-tile 32x32
    const int wr = w >> 2;
    const int wc = w & 3;

    f32x4 acc[2][2] = {};
    u16* bufs[2] = { Abuf0, Abuf1 };

    // ---- prologue: prep chunk 0 into Abuf0 (each thread 32 float4) ----
#pragma unroll
    for (int g = 0; g < 4; ++g) {
        float4 er[8];
#pragma unroll
        for (int j = 0; j < 8; ++j) {
            long e = (long)g * 1048576 + (long)j * 131072 + gt;
            er[j] = E4[(e >> 10) * N_NODES + (e & 1023)];
        }
#pragma unroll
        for (int j = 0; j < 8; ++j) {
            long e = (long)g * 1048576 + (long)j * 131072 + gt;
            Abuf0[e] = f2bf(er[j].x * w0 + er[j].y * w1 + er[j].z * w2 + er[j].w * w3);
        }
    }
    __threadfence();
    grid.sync();

    // ---- main: 4 chunks ----
    for (int z = 0; z < 4; ++z) {
        const u16* Acur = bufs[z & 1];
        u16* Anext = bufs[(z + 1) & 1];
        const bool doprep = (z < 3);

        for (int g = 0; g < 4; ++g) {
            float4 er[8];
            if (doprep) {
#pragma unroll
                for (int j = 0; j < 8; ++j) {
                    long e = (long)g * 1048576 + (long)j * 131072 + gt;
                    er[j] = E4[(e >> 10) * N_NODES + (long)(z + 1) * 1024 + (e & 1023)];
                }
            }
            // 8 MFMA iters on chunk z (local k = g*256 + it*32)
            for (int it = 0; it < 8; ++it) {
                const int kt = g * 256 + it * 32;
                __syncthreads();
                if (w < 4)
                    async16(&Acur[(long)(brow + srA) * 1024 + kt + sc], &As[(w & 3) * 16][0]);
                async16(&ST[(long)(bcol + srB) * N_NODES + z * 1024 + kt + sc], &Bs[w * 16][0]);
                __syncthreads();

                bf16x8 af[2], bfr[2];
#pragma unroll
                for (int m = 0; m < 2; ++m)
                    af[m] = *(const bf16x8*)&As[wr * 32 + m * 16 + (lane & 15)][(lane >> 4) * 8];
#pragma unroll
                for (int n = 0; n < 2; ++n)
                    bfr[n] = *(const bf16x8*)&Bs[wc * 32 + n * 16 + (lane & 15)][(lane >> 4) * 8];
#pragma unroll
                for (int m = 0; m < 2; ++m)
#pragma unroll
                    for (int n = 0; n < 2; ++n)
                        acc[m][n] = __builtin_amdgcn_mfma_f32_16x16x32_bf16(af[m], bfr[n], acc[m][n], 0, 0, 0);
            }
            if (doprep) {
#pragma unroll
                for (int j = 0; j < 8; ++j) {
                    long e = (long)g * 1048576 + (long)j * 131072 + gt;
                    Anext[e] = f2bf(er[j].x * w0 + er[j].y * w1 + er[j].z * w2 + er[j].w * w3);
                }
            }
        }
        if (z < 3) {
            __threadfence();
            grid.sync();
        }
    }

    // ---- epilogue: C/D layout col=lane&15, row=(lane>>4)*4+reg (verified R1-R8) ----
#pragma unroll
    for (int m = 0; m < 2; ++m)
#pragma unroll
        for (int n = 0; n < 2; ++n) {
            int col  = bcol + wc * 32 + n * 16 + (lane & 15);
            int row0 = brow + wr * 32 + m * 16 + (lane >> 4) * 4;
            float bv = bias[col];
#pragma unroll
            for (int r = 0; r < 4; ++r)
                out[(long)(row0 + r) * OUTF_ + col] = acc[m][n][r] + bv;
        }
}

extern "C" void kernel_launch(void* const* d_in, const int* in_sizes, int n_in,
                              void* d_out, int out_size, void* d_ws, size_t ws_size,
                              hipStream_t stream) {
    const float* X    = (const float*)d_in[0];
    // d_in[1] = adj, unused by forward
    const float* E    = (const float*)d_in[2];
    const float* W    = (const float*)d_in[3];
    const float* wq   = (const float*)d_in[4];
    const float* bias = (const float*)d_in[5];
    float* out = (float*)d_out;

    char* ws = (char*)d_ws;
    u16* ST  = (u16*)ws;                     // 512 x 4096 bf16 (support^T), 4 MB
    u16* Xbf = (u16*)(ws + (4l << 20));      // 4096 x 512 bf16, 4 MB
    u16* WT  = (u16*)(ws + (8l << 20));      // 512 x 512 bf16, 0.5 MB
    u16* A0  = (u16*)(ws + (9l << 20));      // 4096 x 1024 bf16 chunk buf, 8 MB
    u16* A1  = (u16*)(ws + (17l << 20));     // 4096 x 1024 bf16 chunk buf, 8 MB

    convert_kernel<<<8192, 256, 0, stream>>>(X, W, Xbf, WT);
    gemm_support<<<dim3(64, 4), 256, 0, stream>>>(Xbf, WT, ST);

    const float4* E4 = (const float4*)E;
    void* args[] = { (void*)&E4, (void*)&wq, (void*)&ST, (void*)&bias,
                     (void*)&A0, (void*)&A1, (void*)&out };
    hipLaunchCooperativeKernel((void*)coop_fused, dim3(256), dim3(512),
                               args, 0, stream);
}

// Round 10
// 148.950 us; speedup vs baseline: 3.0917x; 3.0917x over previous
//
#include <hip/hip_runtime.h>
#include <hip/hip_bf16.h>
#include <stdint.h>

#define N_NODES 4096
#define INF_ 512
#define OUTF_ 512

typedef unsigned short u16;
typedef __attribute__((ext_vector_type(8))) short bf16x8;
typedef __attribute__((ext_vector_type(4))) float f32x4;

__device__ __forceinline__ u16 f2bf(float f) {
    union { float f; uint32_t u; } v; v.f = f;
    uint32_t u = v.u;
    uint32_t r = u + 0x7FFFu + ((u >> 16) & 1u);   // round-to-nearest-even
    return (u16)(r >> 16);
}
__device__ __forceinline__ float bf2f(u16 h) {
    union { uint32_t u; float f; } v; v.u = ((uint32_t)h) << 16;
    return v.f;
}

__device__ __forceinline__ void async16(const void* gsrc, void* ldst) {
    __builtin_amdgcn_global_load_lds(
        (const __attribute__((address_space(1))) unsigned int*)gsrc,
        (__attribute__((address_space(3))) unsigned int*)ldst,
        16, 0, 0);
}

// ---- convert X -> bf16 row-major, W -> bf16 transposed [OUTF][INF] (R2-proven) ----
__global__ void convert_kernel(const float* __restrict__ X, const float* __restrict__ W,
                               u16* __restrict__ Xbf, u16* __restrict__ WT) {
    int tid = blockIdx.x * blockDim.x + threadIdx.x;
    if (tid < N_NODES * INF_) Xbf[tid] = f2bf(X[tid]);
    if (tid < INF_ * OUTF_) {
        int n = tid >> 9, k = tid & 511;
        WT[tid] = f2bf(W[k * OUTF_ + n]);   // WT[n][k] = W[k][n]
    }
}

// ---- gemm1: ST = (X @ W)^T bf16. 64x128 tile, BK=32, 4 waves. (verified R2-R9) ----
__global__ __launch_bounds__(256)
void gemm_support(const u16* __restrict__ A, const u16* __restrict__ B,
                  u16* __restrict__ outT) {
    const int K = 512;
    __shared__ u16 As[64][32];
    __shared__ u16 Bs[128][32];

    const int tid  = threadIdx.x;
    const int lane = tid & 63;
    const int w    = tid >> 6;
    const int wr   = w >> 1;
    const int wc   = w & 1;
    const int brow = blockIdx.x * 64;
    const int bcol = blockIdx.y * 128;

    f32x4 acc[2][4] = {};

    const int srA = w * 16 + (lane >> 2);
    const int srB = w * 32 + (lane >> 2);
    const int sc  = (lane & 3) * 8;

    for (int kt = 0; kt < K; kt += 32) {
        __syncthreads();
        async16(&A[(long)(brow + srA) * K + kt + sc],      &As[w * 16][0]);
        async16(&B[(long)(bcol + srB) * K + kt + sc],      &Bs[w * 32][0]);
        async16(&B[(long)(bcol + srB + 16) * K + kt + sc], &Bs[w * 32 + 16][0]);
        __syncthreads();

        bf16x8 af[2], bfr[4];
#pragma unroll
        for (int m = 0; m < 2; ++m)
            af[m] = *(const bf16x8*)&As[wr * 32 + m * 16 + (lane & 15)][(lane >> 4) * 8];
#pragma unroll
        for (int n = 0; n < 4; ++n)
            bfr[n] = *(const bf16x8*)&Bs[wc * 64 + n * 16 + (lane & 15)][(lane >> 4) * 8];
#pragma unroll
        for (int m = 0; m < 2; ++m)
#pragma unroll
            for (int n = 0; n < 4; ++n)
                acc[m][n] = __builtin_amdgcn_mfma_f32_16x16x32_bf16(af[m], bfr[n], acc[m][n], 0, 0, 0);
    }

#pragma unroll
    for (int m = 0; m < 2; ++m)
#pragma unroll
        for (int n = 0; n < 4; ++n) {
            int col  = bcol + wc * 64 + n * 16 + (lane & 15);
            int row0 = brow + wr * 32 + m * 16 + (lane >> 4) * 4;
#pragma unroll
            for (int r = 0; r < 4; ++r)
                outT[(long)col * N_NODES + row0 + r] = f2bf(acc[m][n][r]);
        }
}

// ---- gemm2 (R8 structure, A-staging swapped to direct-E): ----
// parts[z] = bf16( reshape(E@wq)[:, zc] @ S[zc, :] ). 128x128 tile, BK=32,
// 16 iters, grid (32,4,8) = 1024 blocks (~3-4/CU TLP). Per iter: A-tile built
// from E (16 coalesced float4/thread -> dot -> ds_write bf16 into padded
// As[128][40]); B staged via async16 (R8-verbatim). E read ONCE from HBM
// (4 bcol-sharers are same-XCD co-resident -> L2 serves 3/4).
__global__ __launch_bounds__(256)
void gemm2_fusedE(const float4* __restrict__ E4, const float* __restrict__ wq,
                  const u16* __restrict__ B, u16* __restrict__ parts) {
    const int K = 4096;
    __shared__ u16 As[128][40];   // padded (ds_write path; 2-way banks only)
    __shared__ u16 Bs[128][32];   // linear (global_load_lds)

    const int tid  = threadIdx.x;
    const int lane = tid & 63;
    const int w    = tid >> 6;        // wave 0..3
    const int wr   = w >> 1;
    const int wc   = w & 1;
    const int brow = blockIdx.x * 128;
    const int bcol = blockIdx.y * 128;
    const int kt0  = blockIdx.z * 512;

    const float w0 = wq[0], w1 = wq[1], w2 = wq[2], w3 = wq[3];

    f32x4 acc[4][4] = {};

    // B staging roles (R8-verbatim)
    const int srB = w * 32 + (lane >> 2);
    const int scB = (lane & 3) * 8;
    // E staging roles: 256 threads cover 8 rows x 32 cols per pass
    const int erow = tid >> 5;        // 0..7
    const int ek   = tid & 31;        // k (float4) within BK

    for (int it = 0; it < 16; ++it) {
        const int kt = kt0 + it * 32;
        __syncthreads();
        // B tile via async16 (completion = next barrier's vmcnt drain)
        async16(&B[(long)(bcol + srB) * K + kt + scB],      &Bs[w * 32][0]);
        async16(&B[(long)(bcol + srB + 16) * K + kt + scB], &Bs[w * 32 + 16][0]);
        // A tile from E: two batches of 8 rows/thread
        float4 ev[8];
#pragma unroll
        for (int j = 0; j < 8; ++j)
            ev[j] = E4[(long)(brow + j * 8 + erow) * N_NODES + kt + ek];
#pragma unroll
        for (int j = 0; j < 8; ++j)
            As[j * 8 + erow][ek] = f2bf(ev[j].x * w0 + ev[j].y * w1 + ev[j].z * w2 + ev[j].w * w3);
#pragma unroll
        for (int j = 0; j < 8; ++j)
            ev[j] = E4[(long)(brow + 64 + j * 8 + erow) * N_NODES + kt + ek];
#pragma unroll
        for (int j = 0; j < 8; ++j)
            As[64 + j * 8 + erow][ek] = f2bf(ev[j].x * w0 + ev[j].y * w1 + ev[j].z * w2 + ev[j].w * w3);
        __syncthreads();

        bf16x8 af[4], bfr[4];
#pragma unroll
        for (int m = 0; m < 4; ++m)
            af[m] = *(const bf16x8*)&As[wr * 64 + m * 16 + (lane & 15)][(lane >> 4) * 8];
#pragma unroll
        for (int n = 0; n < 4; ++n)
            bfr[n] = *(const bf16x8*)&Bs[wc * 64 + n * 16 + (lane & 15)][(lane >> 4) * 8];
#pragma unroll
        for (int m = 0; m < 4; ++m)
#pragma unroll
            for (int n = 0; n < 4; ++n)
                acc[m][n] = __builtin_amdgcn_mfma_f32_16x16x32_bf16(af[m], bfr[n], acc[m][n], 0, 0, 0);
    }

    // epilogue -> bf16 partials (R8-verbatim). C/D: col=lane&15, row=(lane>>4)*4+reg
    u16* outP = parts + (long)blockIdx.z * (N_NODES * OUTF_);
#pragma unroll
    for (int m = 0; m < 4; ++m)
#pragma unroll
        for (int n = 0; n < 4; ++n) {
            int col  = bcol + wc * 64 + n * 16 + (lane & 15);
            int row0 = brow + wr * 64 + m * 16 + (lane >> 4) * 4;
#pragma unroll
            for (int r = 0; r < 4; ++r)
                outP[(long)(row0 + r) * OUTF_ + col] = f2bf(acc[m][n][r]);
        }
}

// ---- reduce 8 bf16 split-K partials + bias -> fp32 out (R8-verified) ----
__global__ void reduce8_kernel(const u16* __restrict__ parts, const float* __restrict__ bias,
                               float* __restrict__ out) {
    const int t = blockIdx.x * blockDim.x + threadIdx.x;   // 256K threads, 8 elems each
    const long base = (long)t * 8;
    const int col0 = (int)(base & (OUTF_ - 1));
    const long stride = (long)N_NODES * OUTF_;

    float s[8];
#pragma unroll
    for (int j = 0; j < 8; ++j) s[j] = bias[col0 + j];
#pragma unroll
    for (int z = 0; z < 8; ++z) {
        bf16x8 v = *(const bf16x8*)(parts + z * stride + base);
#pragma unroll
        for (int j = 0; j < 8; ++j) s[j] += bf2f((u16)v[j]);
    }
    float4* o4 = (float4*)(out + base);
    o4[0] = make_float4(s[0], s[1], s[2], s[3]);
    o4[1] = make_float4(s[4], s[5], s[6], s[7]);
}

extern "C" void kernel_launch(void* const* d_in, const int* in_sizes, int n_in,
                              void* d_out, int out_size, void* d_ws, size_t ws_size,
                              hipStream_t stream) {
    const float* X    = (const float*)d_in[0];
    // d_in[1] = adj, unused by forward
    const float* E    = (const float*)d_in[2];
    const float* W    = (const float*)d_in[3];
    const float* wq   = (const float*)d_in[4];
    const float* bias = (const float*)d_in[5];
    float* out = (float*)d_out;

    char* ws = (char*)d_ws;
    u16* ST    = (u16*)ws;                     // 512 x 4096 bf16 (support^T), 4 MB
    u16* Xbf   = (u16*)(ws + (4l << 20));      // 4096 x 512 bf16, 4 MB
    u16* WT    = (u16*)(ws + (8l << 20));      // 512 x 512 bf16, 0.5 MB
    u16* parts = (u16*)(ws + (9l << 20));      // 8 x 4096 x 512 bf16, 32 MB

    // 1) converts (~2us)
    convert_kernel<<<8192, 256, 0, stream>>>(X, W, Xbf, WT);
    // 2) ST = (X@W)^T bf16 (~5us)
    gemm_support<<<dim3(64, 4), 256, 0, stream>>>(Xbf, WT, ST);
    // 3) parts[z] = reshape(E@wq)[:,zc] @ S[zc,:] — E streamed once, in-GEMM
    gemm2_fusedE<<<dim3(32, 4, 8), 256, 0, stream>>>((const float4*)E, wq, ST, parts);
    // 4) out = sum_z parts[z] + bias (~6us)
    reduce8_kernel<<<1024, 256, 0, stream>>>(parts, bias, out);
}